// Round 1
// baseline (158.852 us; speedup 1.0000x reference)
//
#include <hip/hip_runtime.h>

// VectorQuantizer gfx950 R5: same R4 algorithm (full 139 KB bf16 codebook in LDS,
// one barrier, barrier-free 64-iter MFMA K-loop, packed u32 argmin keys), but the
// block is now 1024 threads = 16 waves (4 waves/SIMD) with each wave owning 32
// rows (mi=0..1) instead of 8 waves x 64 rows. LDS already forced 1 block/CU;
// waves/CU was the free occupancy axis. Doubles latency hiding in every phase
// (stage, A-frag x loads, ds_read->MFMA->min chain, gather/store epilogue).
// dist2[n,k] = ||x||^2 - 2 x.e_k + ||e_k||^2 ; argmin invariant to ||x||^2.
// A-fragments hold bf16(-2x) (exact pow2 scale); MFMA C-operand initialized to
// cc = 0.5 + ||e_k||^2 so the MFMA output IS the score s in [0.375,0.625] (>0 =>
// IEEE bits order-monotonic). key = (bits(s) & ~1023) | code; argmin = v_min_u32.
// LDS row stride 68 ushorts: B-frag ds_read_b128 lands on 16 even banks, 2-way
// aliasing only (free per m136). Grid = 256 blocks = exactly 1 block/CU.

typedef __attribute__((ext_vector_type(8))) short short8;
typedef __attribute__((ext_vector_type(4))) float f32x4;

#define VQ_D 64
#define MTILE 512   // rows per block (16 waves x 32 rows)
#define NTHREADS 1024
#define CSTRIDE 68  // ushorts per code row in LDS (64 data + 4 pad)

__device__ inline unsigned short f2bf(float f) {
  union { float f; unsigned u; } v; v.f = f;
  unsigned r = v.u + 0x7FFFu + ((v.u >> 16) & 1u);  // RNE
  return (unsigned short)(r >> 16);
}

// Prep: one wave per codebook row. c2b[k] = 0.5 + ||e_k||^2 ; codebook -> bf16.
// Also zeroes the sse accumulator and completion counter.
__global__ __launch_bounds__(256) void vq_prep(const float* __restrict__ cb,
                                               float* __restrict__ c2b,
                                               unsigned short* __restrict__ cbb,
                                               float* __restrict__ sse,
                                               unsigned* __restrict__ counter, int K) {
  if (blockIdx.x == 0 && threadIdx.x == 0) { *sse = 0.f; *counter = 0u; }
  int w = (int)((blockIdx.x * 256 + threadIdx.x) >> 6);
  int lane = threadIdx.x & 63;
  if (w >= K) return;
  float v = cb[(size_t)w * VQ_D + lane];
  cbb[(size_t)w * VQ_D + lane] = f2bf(v);
  float s = v * v;
#pragma unroll
  for (int off = 32; off; off >>= 1) s += __shfl_down(s, off);
  if (lane == 0) c2b[w] = s + 0.5f;
}

__global__ __launch_bounds__(NTHREADS) void vq_main(
    const float* __restrict__ x, const float* __restrict__ cb,
    const float* __restrict__ c2b, const unsigned short* __restrict__ cbb,
    float* __restrict__ out, float* __restrict__ sse_out,
    unsigned* __restrict__ counter, int nblocks) {
  __shared__ unsigned short cbs[1024 * CSTRIDE];  // 139264 B
  __shared__ float c2s[1024];                     // 4096 B
  __shared__ int idxs[MTILE];                     // 2048 B
  __shared__ float redbuf[16];

  const int tid = threadIdx.x;
  const int wave = tid >> 6;
  const int lane = tid & 63;
  const int quad = lane >> 4;
  const int col = lane & 15;
  const long blockRow0 = (long)blockIdx.x * MTILE;
  const int waveRow0 = wave * 32;  // 16 waves x 32 rows

  // ---- Stage full bf16 codebook (128 KB) into padded LDS. Coalesced 16B chunks.
  // 8192 chunks / 1024 threads = 8 iters; chunk id -> code = id>>3, piece = id&7.
#pragma unroll
  for (int r = 0; r < 8; ++r) {
    int id = r * NTHREADS + tid;
    int code = id >> 3;
    int piece = id & 7;
    short8 v = *(const short8*)(cbb + (size_t)code * VQ_D + piece * 8);
    *(short8*)(cbs + code * CSTRIDE + piece * 8) = v;
  }
  c2s[tid] = c2b[tid];

  // ---- A fragments: bf16(-2*x). A[m=lane&15][k=quad*8+j], rows mi*16+col.
  short8 Af[2][2];
#pragma unroll
  for (int mi = 0; mi < 2; ++mi) {
#pragma unroll
    for (int ks = 0; ks < 2; ++ks) {
      long row = blockRow0 + waveRow0 + mi * 16 + col;
      const f32x4* xp = (const f32x4*)(x + row * VQ_D + ks * 32 + quad * 8);
      f32x4 lo = xp[0];
      f32x4 hi = xp[1];
      short8 a;
      a[0] = (short)f2bf(-2.f * lo[0]); a[1] = (short)f2bf(-2.f * lo[1]);
      a[2] = (short)f2bf(-2.f * lo[2]); a[3] = (short)f2bf(-2.f * lo[3]);
      a[4] = (short)f2bf(-2.f * hi[0]); a[5] = (short)f2bf(-2.f * hi[1]);
      a[6] = (short)f2bf(-2.f * hi[2]); a[7] = (short)f2bf(-2.f * hi[3]);
      Af[mi][ks] = a;
    }
  }

  unsigned bk[2][4];
#pragma unroll
  for (int mi = 0; mi < 2; ++mi)
#pragma unroll
    for (int r = 0; r < 4; ++r) bk[mi][r] = 0xFFFFFFFFu;

  __syncthreads();  // codebook fully staged; the ONLY barrier before the epilogue

  // ---- Barrier-free K-loop: 64 iters x 16 codes. LDS + MFMA + VALU only.
  const unsigned short* bbase = cbs + (size_t)col * CSTRIDE + quad * 8;
#pragma unroll 4
  for (int t = 0; t < 64; ++t) {
    const unsigned short* bp = bbase + t * 16 * CSTRIDE;
    short8 b0 = *(const short8*)bp;
    short8 b1 = *(const short8*)(bp + 32);
    float cc = c2s[t * 16 + col];

    f32x4 acc[2];
#pragma unroll
    for (int mi = 0; mi < 2; ++mi) {
      f32x4 a = {cc, cc, cc, cc};
      a = __builtin_amdgcn_mfma_f32_16x16x32_bf16(Af[mi][0], b0, a, 0, 0, 0);
      a = __builtin_amdgcn_mfma_f32_16x16x32_bf16(Af[mi][1], b1, a, 0, 0, 0);
      acc[mi] = a;
    }

    const unsigned code = (unsigned)((t << 4) + col);
#pragma unroll
    for (int mi = 0; mi < 2; ++mi)
#pragma unroll
      for (int r = 0; r < 4; ++r)
        bk[mi][r] = min(bk[mi][r], (__float_as_uint(acc[mi][r]) & 0xFFFFFC00u) | code);
  }

  // ---- Reduce keys across the 16 columns of each quad group.
#pragma unroll
  for (int off = 1; off < 16; off <<= 1) {
#pragma unroll
    for (int mi = 0; mi < 2; ++mi)
#pragma unroll
      for (int r = 0; r < 4; ++r) {
        unsigned o = (unsigned)__shfl_xor((int)bk[mi][r], off);
        bk[mi][r] = min(bk[mi][r], o);
      }
  }
  if (col == 0) {
#pragma unroll
    for (int mi = 0; mi < 2; ++mi)
#pragma unroll
      for (int r = 0; r < 4; ++r)
        idxs[waveRow0 + mi * 16 + quad * 4 + r] = (int)(bk[mi][r] & 1023u);
  }
  __syncthreads();

  // ---- Gather quantized rows in exact fp32 + SSE for the loss. Coalesced float4.
  float sse = 0.f;
  const f32x4* cb4 = (const f32x4*)cb;
  const f32x4* x4 = (const f32x4*)x;
  f32x4* out4 = (f32x4*)out;
#pragma unroll
  for (int i = 0; i < 8; ++i) {
    int f = i * NTHREADS + tid;  // float4 index within the 512x16 tile
    int row_l = f >> 4;
    int d4 = f & 15;
    int idx = idxs[row_l];
    f32x4 cv = cb4[(size_t)idx * 16 + d4];
    long gi = (blockRow0 + row_l) * 16 + d4;
    f32x4 xv = x4[gi];
    out4[gi] = cv;
    f32x4 dv = cv - xv;
    sse += dv[0] * dv[0] + dv[1] * dv[1] + dv[2] * dv[2] + dv[3] * dv[3];
  }
#pragma unroll
  for (int off = 32; off; off >>= 1) sse += __shfl_down(sse, off);
  if (lane == 0) redbuf[wave] = sse;
  __syncthreads();

  if (tid == 0) {
    float s = 0.f;
#pragma unroll
    for (int w = 0; w < 16; ++w) s += redbuf[w];
    atomicAdd(sse_out, s);
    __threadfence();
    unsigned old = atomicAdd(counter, 1u);
    if (old == (unsigned)(nblocks - 1)) {
      float tot = atomicAdd(sse_out, 0.f);
      long nelem = (long)nblocks * MTILE * VQ_D;
      out[nelem] = 1.25f * tot / (float)nelem;
    }
  }
}

extern "C" void kernel_launch(void* const* d_in, const int* in_sizes, int n_in,
                              void* d_out, int out_size, void* d_ws, size_t ws_size,
                              hipStream_t stream) {
  const float* x = (const float*)d_in[0];
  const float* cb = (const float*)d_in[1];
  float* out = (float*)d_out;

  const long n_elem = (long)in_sizes[0];   // 8388608
  const int nrows = (int)(n_elem / VQ_D);  // 131072
  const int K = in_sizes[1] / VQ_D;        // 1024
  const int nblocks = nrows / MTILE;       // 256

  char* ws = (char*)d_ws;
  float* sse = (float*)ws;                             // 4 B
  unsigned* counter = (unsigned*)(ws + 64);            // 4 B
  float* c2b = (float*)(ws + 256);                     // 4 KB
  unsigned short* cbb = (unsigned short*)(ws + 8192);  // 128 KB bf16 codebook

  vq_prep<<<dim3((K * 64 + 255) / 256), dim3(256), 0, stream>>>(cb, c2b, cbb, sse, counter, K);
  vq_main<<<dim3(nblocks), dim3(1024), 0, stream>>>(x, cb, c2b, cbb, out, sse, counter, nblocks);
}

// Round 2
// 121.801 us; speedup vs baseline: 1.3042x; 1.3042x over previous
//
#include <hip/hip_runtime.h>

// VectorQuantizer gfx950 R6: codebook-in-REGISTERS K-loop (no ds_read on the
// critical path). R5 post-mortem showed the stall is the per-iter
// ds_read->MFMA->min dependency chain, not occupancy. New structure:
//  - 8 waves/block, 512 threads, MTILE=512 rows, grid=256 (1 block/CU).
//  - Wave w holds B-fragments for codes [128w,128w+128) in 64 VGPRs + cc in 8,
//    loaded ONCE from global (L2-resident bf16 codebook from vq_prep).
//  - LDS holds the x-tile as bf16(-2x), 512 rows x stride 68 (~70 KB).
//  - 8 stages: in stage s, wave w computes row-group (w+s)&7 (64 rows) vs its
//    128 codes: 64 register-only MFMAs + packed-key v_min. A-frags for the next
//    group are double-buffered ds_reads, hidden under the MFMA block.
//  - Per-row argmin merged across waves via ds_atomic_min on keys[512]; the
//    packed key (score bits &~1023 | code) gives the same total order as R4.
// dist2[n,k] = ||x||^2 - 2 x.e_k + ||e_k||^2 ; argmin invariant to ||x||^2.
// MFMA C-init cc = 0.5 + ||e_k||^2 => output s in [0.375,0.625] > 0 => IEEE
// bits order-monotonic.

typedef __attribute__((ext_vector_type(8))) short short8;
typedef __attribute__((ext_vector_type(4))) float f32x4;

#define VQ_D 64
#define MTILE 512
#define NTH 512
#define AS 68  // ushorts per x row in LDS (64 data + 4 pad); same bank pattern as R4 (measured 0 conflicts)

__device__ inline unsigned short f2bf(float f) {
  union { float f; unsigned u; } v; v.f = f;
  unsigned r = v.u + 0x7FFFu + ((v.u >> 16) & 1u);  // RNE
  return (unsigned short)(r >> 16);
}

// Prep: one wave per codebook row. c2b[k] = 0.5 + ||e_k||^2 ; codebook -> bf16.
// Also zeroes the sse accumulator and completion counter.
__global__ __launch_bounds__(256) void vq_prep(const float* __restrict__ cb,
                                               float* __restrict__ c2b,
                                               unsigned short* __restrict__ cbb,
                                               float* __restrict__ sse,
                                               unsigned* __restrict__ counter, int K) {
  if (blockIdx.x == 0 && threadIdx.x == 0) { *sse = 0.f; *counter = 0u; }
  int w = (int)((blockIdx.x * 256 + threadIdx.x) >> 6);
  int lane = threadIdx.x & 63;
  if (w >= K) return;
  float v = cb[(size_t)w * VQ_D + lane];
  cbb[(size_t)w * VQ_D + lane] = f2bf(v);
  float s = v * v;
#pragma unroll
  for (int off = 32; off; off >>= 1) s += __shfl_down(s, off);
  if (lane == 0) c2b[w] = s + 0.5f;
}

#define LOADA(DST, G)                                                                  \
  {                                                                                    \
    const int g_ = (G);                                                                \
    _Pragma("unroll") for (int mi_ = 0; mi_ < 4; ++mi_) {                              \
      _Pragma("unroll") for (int ks_ = 0; ks_ < 2; ++ks_) {                            \
        DST[mi_][ks_] = *(const short8*)(xb + (g_ * 64 + mi_ * 16 + col) * AS +        \
                                         ks_ * 32 + quad * 8);                         \
      }                                                                                \
    }                                                                                  \
  }

__global__ __launch_bounds__(NTH) void vq_main(
    const float* __restrict__ x, const float* __restrict__ cb,
    const float* __restrict__ c2b, const unsigned short* __restrict__ cbb,
    float* __restrict__ out, float* __restrict__ sse_out,
    unsigned* __restrict__ counter, int nblocks) {
  __shared__ unsigned short xb[MTILE * AS];  // 69632 B
  __shared__ unsigned keys[MTILE];           // 2048 B
  __shared__ float redbuf[8];

  const int tid = threadIdx.x;
  const int wave = tid >> 6;
  const int lane = tid & 63;
  const int quad = lane >> 4;
  const int col = lane & 15;
  const long blockRow0 = (long)blockIdx.x * MTILE;

  // ---- This wave's resident codebook slice: 128 codes in registers.
  // B-frag layout identical to R4's LDS read: lane(quad,col) holds code
  // (ci*16+col), dims [ks*32+quad*8, +8).
  short8 B[8][2];
  float cc[8];
  const int code0 = wave * 128;
#pragma unroll
  for (int ci = 0; ci < 8; ++ci) {
    const unsigned short* bp = cbb + (size_t)(code0 + ci * 16 + col) * VQ_D + quad * 8;
    B[ci][0] = *(const short8*)bp;
    B[ci][1] = *(const short8*)(bp + 32);
    cc[ci] = c2b[code0 + ci * 16 + col];
  }

  keys[tid] = 0xFFFFFFFFu;  // NTH == MTILE

  // ---- Stage x tile as bf16(-2x) into LDS. 4096 short8 chunks / 512 thr = 8 it.
  // id -> row = id>>3, piece = id&7; global reads are fully sequential 32B.
#pragma unroll
  for (int i = 0; i < 8; ++i) {
    int id = i * NTH + tid;
    int row = id >> 3;
    int piece = id & 7;
    const f32x4* xp = (const f32x4*)(x + (blockRow0 + row) * VQ_D + piece * 8);
    f32x4 lo = xp[0];
    f32x4 hi = xp[1];
    short8 a;
    a[0] = (short)f2bf(-2.f * lo[0]); a[1] = (short)f2bf(-2.f * lo[1]);
    a[2] = (short)f2bf(-2.f * lo[2]); a[3] = (short)f2bf(-2.f * lo[3]);
    a[4] = (short)f2bf(-2.f * hi[0]); a[5] = (short)f2bf(-2.f * hi[1]);
    a[6] = (short)f2bf(-2.f * hi[2]); a[7] = (short)f2bf(-2.f * hi[3]);
    *(short8*)(xb + row * AS + piece * 8) = a;
  }
  __syncthreads();  // x tile staged + keys initialized; only barrier before epilogue

  // ---- 8 stages: register-resident MFMA block, A-frags double-buffered.
  short8 Ac[4][2], An[4][2];
  LOADA(Ac, wave & 7);
  for (int s = 0; s < 8; ++s) {
    const int g = (wave + s) & 7;
    LOADA(An, (wave + s + 1) & 7);  // s=7 wraps to own group: valid, unused

    unsigned bk[4][4];
#pragma unroll
    for (int mi = 0; mi < 4; ++mi)
#pragma unroll
      for (int r = 0; r < 4; ++r) bk[mi][r] = 0xFFFFFFFFu;

#pragma unroll
    for (int mi = 0; mi < 4; ++mi) {
#pragma unroll
      for (int ci = 0; ci < 8; ++ci) {
        f32x4 a = {cc[ci], cc[ci], cc[ci], cc[ci]};
        a = __builtin_amdgcn_mfma_f32_16x16x32_bf16(Ac[mi][0], B[ci][0], a, 0, 0, 0);
        a = __builtin_amdgcn_mfma_f32_16x16x32_bf16(Ac[mi][1], B[ci][1], a, 0, 0, 0);
        const unsigned code = (unsigned)(code0 + ci * 16 + col);
#pragma unroll
        for (int r = 0; r < 4; ++r)
          bk[mi][r] = min(bk[mi][r], (__float_as_uint(a[r]) & 0xFFFFFC00u) | code);
      }
    }

    // Reduce keys across the 16 columns of each quad group, then merge by row.
#pragma unroll
    for (int off = 1; off < 16; off <<= 1) {
#pragma unroll
      for (int mi = 0; mi < 4; ++mi)
#pragma unroll
        for (int r = 0; r < 4; ++r) {
          unsigned o = (unsigned)__shfl_xor((int)bk[mi][r], off);
          bk[mi][r] = min(bk[mi][r], o);
        }
    }
    if (col == 0) {
#pragma unroll
      for (int mi = 0; mi < 4; ++mi)
#pragma unroll
        for (int r = 0; r < 4; ++r)
          atomicMin(&keys[g * 64 + mi * 16 + quad * 4 + r], bk[mi][r]);
    }

#pragma unroll
    for (int mi = 0; mi < 4; ++mi)
#pragma unroll
      for (int ks = 0; ks < 2; ++ks) Ac[mi][ks] = An[mi][ks];
  }
  __syncthreads();

  // ---- Gather quantized rows in exact fp32 + SSE for the loss. Coalesced float4.
  float sse = 0.f;
  const f32x4* cb4 = (const f32x4*)cb;
  const f32x4* x4 = (const f32x4*)x;
  f32x4* out4 = (f32x4*)out;
#pragma unroll
  for (int i = 0; i < 16; ++i) {
    int f = i * NTH + tid;  // float4 index within the 512x16 tile
    int row_l = f >> 4;
    int d4 = f & 15;
    int idx = (int)(keys[row_l] & 1023u);
    f32x4 cv = cb4[(size_t)idx * 16 + d4];
    long gi = (blockRow0 + row_l) * 16 + d4;
    f32x4 xv = x4[gi];
    out4[gi] = cv;
    f32x4 dv = cv - xv;
    sse += dv[0] * dv[0] + dv[1] * dv[1] + dv[2] * dv[2] + dv[3] * dv[3];
  }
#pragma unroll
  for (int off = 32; off; off >>= 1) sse += __shfl_down(sse, off);
  if (lane == 0) redbuf[wave] = sse;
  __syncthreads();

  if (tid == 0) {
    float s = 0.f;
#pragma unroll
    for (int w = 0; w < 8; ++w) s += redbuf[w];
    atomicAdd(sse_out, s);
    __threadfence();
    unsigned old = atomicAdd(counter, 1u);
    if (old == (unsigned)(nblocks - 1)) {
      float tot = atomicAdd(sse_out, 0.f);
      long nelem = (long)nblocks * MTILE * VQ_D;
      out[nelem] = 1.25f * tot / (float)nelem;
    }
  }
}

extern "C" void kernel_launch(void* const* d_in, const int* in_sizes, int n_in,
                              void* d_out, int out_size, void* d_ws, size_t ws_size,
                              hipStream_t stream) {
  const float* x = (const float*)d_in[0];
  const float* cb = (const float*)d_in[1];
  float* out = (float*)d_out;

  const long n_elem = (long)in_sizes[0];   // 8388608
  const int nrows = (int)(n_elem / VQ_D);  // 131072
  const int K = in_sizes[1] / VQ_D;        // 1024
  const int nblocks = nrows / MTILE;       // 256

  char* ws = (char*)d_ws;
  float* sse = (float*)ws;                             // 4 B
  unsigned* counter = (unsigned*)(ws + 64);            // 4 B
  float* c2b = (float*)(ws + 256);                     // 4 KB
  unsigned short* cbb = (unsigned short*)(ws + 8192);  // 128 KB bf16 codebook

  vq_prep<<<dim3((K * 64 + 255) / 256), dim3(256), 0, stream>>>(cb, c2b, cbb, sse, counter, K);
  vq_main<<<dim3(nblocks), dim3(NTH), 0, stream>>>(x, cb, c2b, cbb, out, sse, counter, nblocks);
}